// Round 4
// baseline (518.984 us; speedup 1.0000x reference)
//
#include <hip/hip_runtime.h>
#include <math.h>

#define HH 224
#define WW 224
#define BB 8
#define NC 196
#define NBHD 10
#define SS 16
#define MW_OVER_S 0.625f   // M_WEIGHT / S = 10.0 / 16 (exactly representable)

// -------------------------------------------------------------------------
// Phase A of _find_minima: for each (batch, centroid) window, compute
//   - min value over the 20x20 (clipped) window
//   - min flat index among pixels equal to the min
//   - count of pixels equal to the min
// Fully parallel: grid (NC, BB), 64 threads (1 wave).
// Two-pass over the window (2nd pass is L1/L2-hot) to avoid runtime-indexed
// per-thread arrays, which would spill to scratch (guide rule #20).
// -------------------------------------------------------------------------
__global__ void k_window_scan(const float* __restrict__ g,
                              float* __restrict__ wmin,
                              int* __restrict__ widx,
                              int* __restrict__ wcnt) {
    int c = blockIdx.x, b = blockIdx.y;
    int lane = threadIdx.x;
    const float* gb = g + b * HH * WW;
    int gy = 8 + 16 * (c / 14), gx = 8 + 16 * (c % 14);
    int y0 = max(0, gy - NBHD), y1 = min(HH, gy + NBHD);
    int x0 = max(0, gx - NBHD), x1 = min(WW, gx + NBHD);
    int wd = x1 - x0;
    int n = (y1 - y0) * wd;

    // pass 1: window min (min-reduce is exact; no fp-ordering concern)
    float m = INFINITY;
    for (int i = lane; i < n; i += 64) {
        int y = y0 + i / wd, x = x0 + i % wd;
        m = fminf(m, gb[y * WW + x]);
    }
    for (int off = 1; off < 64; off <<= 1)
        m = fminf(m, __shfl_xor(m, off));

    // pass 2: count equals + min flat index among equals
    int bidx = 0x7fffffff;
    int cnt = 0;
    for (int i = lane; i < n; i += 64) {
        int y = y0 + i / wd, x = x0 + i % wd;
        int f = y * WW + x;
        if (gb[f] == m) { bidx = min(bidx, f); ++cnt; }
    }
    for (int off = 1; off < 64; off <<= 1) {
        bidx = min(bidx, __shfl_xor(bidx, off));
        cnt += __shfl_xor(cnt, off);
    }
    if (lane == 0) {
        wmin[b * NC + c] = m;
        widx[b * NC + c] = bidx;
        wcnt[b * NC + c] = cnt;
    }
}

// -------------------------------------------------------------------------
// Phase B of _find_minima: sequential occupancy resolve per batch (the
// reference's scan carries an occupancy grid, so this part is inherently
// serial in c). One block (1 wave) per batch; occ bitmap in LDS.
// Reference semantics: chosen = first FREE pixel equal to the window min
// (avail = wm & (g==mval) & ~occ). The expensive window rescan only
// triggers when (count>1 AND the min-flat-index equal pixel is occupied).
// Tail: gather initial cluster colors at the found centroids (fused to
// save a kernel launch).
// -------------------------------------------------------------------------
__global__ void k_resolve(const float* __restrict__ g,
                          const float* __restrict__ x,
                          const float* __restrict__ wmin,
                          const int* __restrict__ widx,
                          const int* __restrict__ wcnt,
                          int* __restrict__ yc, int* __restrict__ xc,
                          float* __restrict__ colors,
                          float* __restrict__ out_cents) {
    __shared__ unsigned char occ[HH * WW];
    __shared__ float s_min[NC];
    __shared__ int s_idx[NC];
    __shared__ int s_cnt[NC];
    int b = blockIdx.x, lane = threadIdx.x;
    const float* gb = g + b * HH * WW;
    // word-wise clear: HH*WW = 50176 bytes = 12544 words (divisible by 4)
    unsigned int* occ32 = (unsigned int*)occ;
    for (int i = lane; i < (HH * WW) / 4; i += 64) occ32[i] = 0u;
    for (int i = lane; i < NC; i += 64) {
        s_min[i] = wmin[b * NC + i];
        s_idx[i] = widx[b * NC + i];
        s_cnt[i] = wcnt[b * NC + i];
    }
    __syncthreads();

    for (int c = 0; c < NC; ++c) {
        int idx = s_idx[c];
        int cnt = s_cnt[c];
        bool occd = (occ[idx] != 0);      // wave-uniform
        int chosen;
        if (cnt == 1) {
            chosen = occd ? -1 : idx;      // unique min: take it, or no move if occupied
        } else if (!occd) {
            chosen = idx;                  // multiple equal, first (min flat index) free
        } else {
            // rare: multiple equal minima and the first is occupied -> rescan
            float m = s_min[c];
            int gy = 8 + 16 * (c / 14), gx = 8 + 16 * (c % 14);
            int y0 = max(0, gy - NBHD), y1 = min(HH, gy + NBHD);
            int x0 = max(0, gx - NBHD), x1 = min(WW, gx + NBHD);
            int wd = x1 - x0;
            int n = (y1 - y0) * wd;
            int best = 0x7fffffff;
            for (int i = lane; i < n; i += 64) {
                int y = y0 + i / wd, x = x0 + i % wd;
                int f = y * WW + x;
                if (gb[f] == m && !occ[f]) best = min(best, f);
            }
            for (int off = 1; off < 64; off <<= 1)
                best = min(best, __shfl_xor(best, off));
            chosen = (best == 0x7fffffff) ? -1 : best;
        }
        int ny, nx;
        if (chosen >= 0) {
            ny = chosen / WW; nx = chosen % WW;
            if (lane == 0) occ[chosen] = 1;
        } else {
            // found=False: keep the ORIGINAL grid centroid (reference keeps c)
            ny = 8 + 16 * (c / 14); nx = 8 + 16 * (c % 14);
        }
        if (lane == 0) {
            yc[b * NC + c] = ny;
            xc[b * NC + c] = nx;
            out_cents[(b * NC + c) * 2 + 0] = (float)ny;
            out_cents[(b * NC + c) * 2 + 1] = (float)nx;
        }
        __syncthreads();  // occ write visible before next iteration's reads
    }

    // fused init-colors: gather x at the found centroids
    const float* xb = x + b * 3 * HH * WW;
    for (int k = lane; k < NC; k += 64) {
        int y = yc[b * NC + k], xx = xc[b * NC + k];
        int idx = y * WW + xx;
        colors[(b * NC + k) * 3 + 0] = xb[idx];
        colors[(b * NC + k) * 3 + 1] = xb[HH * WW + idx];
        colors[(b * NC + k) * 3 + 2] = xb[2 * HH * WW + idx];
    }
}

// -------------------------------------------------------------------------
// Assignment: one 16x16 tile per block. Stage all centroids, build a
// candidate list via bbox intersect (~4-9 candidates/tile), then per-pixel
// argmin. Labels written as float into d_out's mask region.
// All distance arithmetic uses _rn intrinsics (no FMA contraction) to match
// the reference's unfused evaluation: cd = sqrt(max(x2 + c2 - 2*cross, 0)),
// dist = cd + 0.625 * sqrt(dy^2 + dx^2).
// Tie-break: lexicographic (d, k) == jnp.argmin first-occurrence.
// -------------------------------------------------------------------------
__global__ void k_assign(const float* __restrict__ x,
                         const int* __restrict__ yc,
                         const int* __restrict__ xc,
                         const float* __restrict__ colors,
                         float* __restrict__ lblf) {
    __shared__ int s_yc[NC], s_xc[NC];
    __shared__ float s_c0[NC], s_c1[NC], s_c2[NC], s_cc[NC];
    __shared__ int s_cand[NC];
    __shared__ int s_n;
    int b = blockIdx.z;
    int ty0 = blockIdx.y * 16, tx0 = blockIdx.x * 16;
    int t = threadIdx.y * 16 + threadIdx.x;
    if (t == 0) s_n = 0;
    __syncthreads();
    if (t < NC) {
        int yck = yc[b * NC + t], xck = xc[b * NC + t];
        s_yc[t] = yck; s_xc[t] = xck;
        float c0 = colors[(b * NC + t) * 3 + 0];
        float c1 = colors[(b * NC + t) * 3 + 1];
        float c2 = colors[(b * NC + t) * 3 + 2];
        s_c0[t] = c0; s_c1[t] = c1; s_c2[t] = c2;
        s_cc[t] = __fadd_rn(__fadd_rn(__fmul_rn(c0, c0), __fmul_rn(c1, c1)), __fmul_rn(c2, c2));
        // window [yck-16,yck+16)x[xck-16,xck+16) intersects tile [ty0,ty0+16)x[tx0,tx0+16)?
        if (yck > ty0 - 17 && yck < ty0 + 32 && xck > tx0 - 17 && xck < tx0 + 32) {
            int p = atomicAdd(&s_n, 1);
            s_cand[p] = t;   // order nondeterministic; tie-break makes it irrelevant
        }
    }
    __syncthreads();

    int h = ty0 + threadIdx.y, w = tx0 + threadIdx.x;
    const float* xb = x + b * 3 * HH * WW;
    int pidx = h * WW + w;
    float x0v = xb[pidx];
    float x1v = xb[HH * WW + pidx];
    float x2v = xb[2 * HH * WW + pidx];
    float px2 = __fadd_rn(__fadd_rn(__fmul_rn(x0v, x0v), __fmul_rn(x1v, x1v)), __fmul_rn(x2v, x2v));
    float hf = (float)h, wf = (float)w;

    float best = INFINITY;
    int bestk = -1;
    int n = s_n;
    for (int i = 0; i < n; ++i) {
        int k = s_cand[i];
        int yck = s_yc[k], xck = s_xc[k];
        if (h >= yck - SS && h < yck + SS && w >= xck - SS && w < xck + SS) {
            float cross = __fadd_rn(__fadd_rn(__fmul_rn(x0v, s_c0[k]), __fmul_rn(x1v, s_c1[k])),
                                    __fmul_rn(x2v, s_c2[k]));
            float t2 = __fsub_rn(__fadd_rn(px2, s_cc[k]), __fmul_rn(2.0f, cross));
            float cd = __fsqrt_rn(fmaxf(t2, 0.0f));
            float dy = __fsub_rn(hf, (float)yck);
            float dx = __fsub_rn(wf, (float)xck);
            float sp = __fsqrt_rn(__fadd_rn(__fmul_rn(dy, dy), __fmul_rn(dx, dx)));
            float d = __fadd_rn(cd, __fmul_rn(MW_OVER_S, sp));
            if (d < best || (d == best && k < bestk)) { best = d; bestk = k; }
        }
    }
    lblf[b * HH * WW + pidx] = (float)bestk;
}

// -------------------------------------------------------------------------
// Update step: one thread per (b, k). Scans the cluster's +-16 window in
// row-major order: cluster-k pixels exist ONLY inside its window (dist=inf
// outside), so this visits them in flat order -> fp32 color sums accumulate
// in the same order as the reference's sequential segment_sum.
// cnt/sy/sx are integer sums (exact in any order; < 2^24).
// -------------------------------------------------------------------------
__global__ void k_update(const float* __restrict__ x,
                         const float* __restrict__ lblf,
                         int* __restrict__ yc, int* __restrict__ xc,
                         float* __restrict__ colors) {
    int b = blockIdx.x, k = threadIdx.x;
    if (k >= NC) return;
    int yck = yc[b * NC + k], xck = xc[b * NC + k];
    int y0 = max(0, yck - SS), y1 = min(HH, yck + SS);
    int x0 = max(0, xck - SS), x1 = min(WW, xck + SS);
    const float* xb = x + b * HH * WW * 3;
    const float* lb = lblf + b * HH * WW;
    float kf = (float)k;
    int cnt = 0, sy = 0, sx = 0;
    float s0 = 0.0f, s1 = 0.0f, s2 = 0.0f;
    for (int y = y0; y < y1; ++y) {
        for (int xx = x0; xx < x1; ++xx) {
            int idx = y * WW + xx;
            if (lb[idx] == kf) {
                ++cnt; sy += y; sx += xx;
                s0 = __fadd_rn(s0, xb[idx]);
                s1 = __fadd_rn(s1, xb[HH * WW + idx]);
                s2 = __fadd_rn(s2, xb[2 * HH * WW + idx]);
            }
        }
    }
    if (cnt > 0) {
        float denom = (float)cnt;
        // reference: round(clip(sum/denom, 0, 223)); jnp.round == rint (half-to-even)
        float nyf = rintf(fminf(fmaxf(__fdiv_rn((float)sy, denom), 0.0f), (float)(HH - 1)));
        float nxf = rintf(fminf(fmaxf(__fdiv_rn((float)sx, denom), 0.0f), (float)(WW - 1)));
        yc[b * NC + k] = (int)nyf;
        xc[b * NC + k] = (int)nxf;
        colors[(b * NC + k) * 3 + 0] = __fdiv_rn(s0, denom);
        colors[(b * NC + k) * 3 + 1] = __fdiv_rn(s1, denom);
        colors[(b * NC + k) * 3 + 2] = __fdiv_rn(s2, denom);
    }
}

// -------------------------------------------------------------------------
// Launch sequence:
//   window_scan -> resolve(+init_colors) -> assign -> update -> assign
// (MAX_ITER=2: only lbl escapes the reference loop, so the 2nd iteration's
//  update is dead and elided.)
// -------------------------------------------------------------------------
extern "C" void kernel_launch(void* const* d_in, const int* in_sizes, int n_in,
                              void* d_out, int out_size, void* d_ws, size_t ws_size,
                              hipStream_t stream) {
    const float* x = (const float*)d_in[0];      // (8,3,224,224) f32
    const float* g = (const float*)d_in[1];      // (8,1,224,224) f32
    float* out = (float*)d_out;
    float* out_cents = out;                      // 8*196*2 floats
    float* lblf = out + BB * NC * 2;             // 8*224*224 floats (labels as f32)

    // workspace layout (all < 64 KB total)
    int* yc = (int*)d_ws;                        // BB*NC
    int* xc = yc + BB * NC;                      // BB*NC
    float* colors = (float*)(xc + BB * NC);      // BB*NC*3
    float* wmin = colors + BB * NC * 3;          // BB*NC
    int* widx = (int*)(wmin + BB * NC);          // BB*NC
    int* wcnt = widx + BB * NC;                  // BB*NC

    dim3 gscan(NC, BB);
    k_window_scan<<<gscan, 64, 0, stream>>>(g, wmin, widx, wcnt);
    k_resolve<<<BB, 64, 0, stream>>>(g, x, wmin, widx, wcnt, yc, xc, colors, out_cents);

    dim3 gridA(WW / 16, HH / 16, BB);
    dim3 blkA(16, 16);
    k_assign<<<gridA, blkA, 0, stream>>>(x, yc, xc, colors, lblf);   // iter 0 assign
    k_update<<<BB, 256, 0, stream>>>(x, lblf, yc, xc, colors);       // iter 0 update
    k_assign<<<gridA, blkA, 0, stream>>>(x, yc, xc, colors, lblf);   // iter 1 assign (final)
}

// Round 6
// 153.889 us; speedup vs baseline: 3.3725x; 3.3725x over previous
//
#include <hip/hip_runtime.h>
#include <math.h>

#define HH 224
#define WW 224
#define BB 8
#define NC 196
#define NBHD 10
#define SS 16
#define MW_OVER_S 0.625f   // M_WEIGHT / S = 10.0 / 16 (exactly representable)

// -------------------------------------------------------------------------
// Phase A of _find_minima: per (batch, centroid) window min / min-flat-index
// among equals / equal count. Fully parallel: grid (NC, BB), 1 wave.
// -------------------------------------------------------------------------
__global__ void k_window_scan(const float* __restrict__ g,
                              float* __restrict__ wmin,
                              int* __restrict__ widx,
                              int* __restrict__ wcnt) {
    int c = blockIdx.x, b = blockIdx.y;
    int lane = threadIdx.x;
    const float* gb = g + b * HH * WW;
    int gy = 8 + 16 * (c / 14), gx = 8 + 16 * (c % 14);
    int y0 = max(0, gy - NBHD), y1 = min(HH, gy + NBHD);
    int x0 = max(0, gx - NBHD), x1 = min(WW, gx + NBHD);
    int wd = x1 - x0;
    int n = (y1 - y0) * wd;

    // pass 1: window min (min-reduce is exact; no fp-ordering concern)
    float m = INFINITY;
    for (int i = lane; i < n; i += 64) {
        int y = y0 + i / wd, x = x0 + i % wd;
        m = fminf(m, gb[y * WW + x]);
    }
    for (int off = 1; off < 64; off <<= 1)
        m = fminf(m, __shfl_xor(m, off));

    // pass 2: count equals + min flat index among equals (L1/L2-hot)
    int bidx = 0x7fffffff;
    int cnt = 0;
    for (int i = lane; i < n; i += 64) {
        int y = y0 + i / wd, x = x0 + i % wd;
        int f = y * WW + x;
        if (gb[f] == m) { bidx = min(bidx, f); ++cnt; }
    }
    for (int off = 1; off < 64; off <<= 1) {
        bidx = min(bidx, __shfl_xor(bidx, off));
        cnt += __shfl_xor(cnt, off);
    }
    if (lane == 0) {
        wmin[b * NC + c] = m;
        widx[b * NC + c] = bidx;
        wcnt[b * NC + c] = cnt;
    }
}

// -------------------------------------------------------------------------
// Phase B of _find_minima: sequential occupancy resolve per batch (the
// reference's scan carries an occupancy grid -> inherently serial in c).
// One block (1 wave) per batch; occ bitmap in LDS. Rescan only when
// (count>1 AND the min-flat-index equal pixel is occupied).
// Tail: fused init-colors gather.
// -------------------------------------------------------------------------
__global__ void k_resolve(const float* __restrict__ g,
                          const float* __restrict__ x,
                          const float* __restrict__ wmin,
                          const int* __restrict__ widx,
                          const int* __restrict__ wcnt,
                          int* __restrict__ yc, int* __restrict__ xc,
                          float* __restrict__ colors,
                          float* __restrict__ out_cents) {
    __shared__ unsigned char occ[HH * WW];
    __shared__ float s_min[NC];
    __shared__ int s_idx[NC];
    __shared__ int s_cnt[NC];
    int b = blockIdx.x, lane = threadIdx.x;
    const float* gb = g + b * HH * WW;
    unsigned int* occ32 = (unsigned int*)occ;
    for (int i = lane; i < (HH * WW) / 4; i += 64) occ32[i] = 0u;
    for (int i = lane; i < NC; i += 64) {
        s_min[i] = wmin[b * NC + i];
        s_idx[i] = widx[b * NC + i];
        s_cnt[i] = wcnt[b * NC + i];
    }
    __syncthreads();

    for (int c = 0; c < NC; ++c) {
        int idx = s_idx[c];
        int cnt = s_cnt[c];
        bool occd = (occ[idx] != 0);      // wave-uniform
        int chosen;
        if (cnt == 1) {
            chosen = occd ? -1 : idx;
        } else if (!occd) {
            chosen = idx;
        } else {
            // rare: multiple equal minima and the first is occupied -> rescan
            float m = s_min[c];
            int gy = 8 + 16 * (c / 14), gx = 8 + 16 * (c % 14);
            int y0 = max(0, gy - NBHD), y1 = min(HH, gy + NBHD);
            int x0 = max(0, gx - NBHD), x1 = min(WW, gx + NBHD);
            int wd = x1 - x0;
            int n = (y1 - y0) * wd;
            int best = 0x7fffffff;
            for (int i = lane; i < n; i += 64) {
                int y = y0 + i / wd, x = x0 + i % wd;
                int f = y * WW + x;
                if (gb[f] == m && !occ[f]) best = min(best, f);
            }
            for (int off = 1; off < 64; off <<= 1)
                best = min(best, __shfl_xor(best, off));
            chosen = (best == 0x7fffffff) ? -1 : best;
        }
        int ny, nx;
        if (chosen >= 0) {
            ny = chosen / WW; nx = chosen % WW;
            if (lane == 0) occ[chosen] = 1;
        } else {
            ny = 8 + 16 * (c / 14); nx = 8 + 16 * (c % 14);
        }
        if (lane == 0) {
            yc[b * NC + c] = ny;
            xc[b * NC + c] = nx;
            out_cents[(b * NC + c) * 2 + 0] = (float)ny;
            out_cents[(b * NC + c) * 2 + 1] = (float)nx;
        }
        __syncthreads();
    }

    // fused init-colors: gather x at the found centroids
    const float* xb = x + b * 3 * HH * WW;
    for (int k = lane; k < NC; k += 64) {
        int y = yc[b * NC + k], xx = xc[b * NC + k];
        int idx = y * WW + xx;
        colors[(b * NC + k) * 3 + 0] = xb[idx];
        colors[(b * NC + k) * 3 + 1] = xb[HH * WW + idx];
        colors[(b * NC + k) * 3 + 2] = xb[2 * HH * WW + idx];
    }
}

// -------------------------------------------------------------------------
// Assignment: one 16x16 tile per block; candidate list via bbox intersect;
// per-pixel argmin with _rn arithmetic (matches reference unfused eval);
// lexicographic (d,k) tie-break == jnp.argmin first-occurrence.
// -------------------------------------------------------------------------
__global__ void k_assign(const float* __restrict__ x,
                         const int* __restrict__ yc,
                         const int* __restrict__ xc,
                         const float* __restrict__ colors,
                         float* __restrict__ lblf) {
    __shared__ int s_yc[NC], s_xc[NC];
    __shared__ float s_c0[NC], s_c1[NC], s_c2[NC], s_cc[NC];
    __shared__ int s_cand[NC];
    __shared__ int s_n;
    int b = blockIdx.z;
    int ty0 = blockIdx.y * 16, tx0 = blockIdx.x * 16;
    int t = threadIdx.y * 16 + threadIdx.x;
    if (t == 0) s_n = 0;
    __syncthreads();
    if (t < NC) {
        int yck = yc[b * NC + t], xck = xc[b * NC + t];
        s_yc[t] = yck; s_xc[t] = xck;
        float c0 = colors[(b * NC + t) * 3 + 0];
        float c1 = colors[(b * NC + t) * 3 + 1];
        float c2 = colors[(b * NC + t) * 3 + 2];
        s_c0[t] = c0; s_c1[t] = c1; s_c2[t] = c2;
        s_cc[t] = __fadd_rn(__fadd_rn(__fmul_rn(c0, c0), __fmul_rn(c1, c1)), __fmul_rn(c2, c2));
        if (yck > ty0 - 17 && yck < ty0 + 32 && xck > tx0 - 17 && xck < tx0 + 32) {
            int p = atomicAdd(&s_n, 1);
            s_cand[p] = t;
        }
    }
    __syncthreads();

    int h = ty0 + threadIdx.y, w = tx0 + threadIdx.x;
    const float* xb = x + b * 3 * HH * WW;
    int pidx = h * WW + w;
    float x0v = xb[pidx];
    float x1v = xb[HH * WW + pidx];
    float x2v = xb[2 * HH * WW + pidx];
    float px2 = __fadd_rn(__fadd_rn(__fmul_rn(x0v, x0v), __fmul_rn(x1v, x1v)), __fmul_rn(x2v, x2v));
    float hf = (float)h, wf = (float)w;

    float best = INFINITY;
    int bestk = -1;
    int n = s_n;
    for (int i = 0; i < n; ++i) {
        int k = s_cand[i];
        int yck = s_yc[k], xck = s_xc[k];
        if (h >= yck - SS && h < yck + SS && w >= xck - SS && w < xck + SS) {
            float cross = __fadd_rn(__fadd_rn(__fmul_rn(x0v, s_c0[k]), __fmul_rn(x1v, s_c1[k])),
                                    __fmul_rn(x2v, s_c2[k]));
            float t2 = __fsub_rn(__fadd_rn(px2, s_cc[k]), __fmul_rn(2.0f, cross));
            float cd = __fsqrt_rn(fmaxf(t2, 0.0f));
            float dy = __fsub_rn(hf, (float)yck);
            float dx = __fsub_rn(wf, (float)xck);
            float sp = __fsqrt_rn(__fadd_rn(__fmul_rn(dy, dy), __fmul_rn(dx, dx)));
            float d = __fadd_rn(cd, __fmul_rn(MW_OVER_S, sp));
            if (d < best || (d == best && k < bestk)) { best = d; bestk = k; }
        }
    }
    lblf[b * HH * WW + pidx] = (float)bestk;
}

// -------------------------------------------------------------------------
// Update step, parallelized: one 256-thread block per (b, k) -> 1568 blocks.
// The reference's segment_sum accumulates cluster-k pixels in flat image
// order; cluster-k pixels exist only inside its +-16 window, and the window's
// row-major order IS flat order. We preserve the EXACT fp add order by:
//   1. parallel match detection (4 window-flat indices per thread, bitmask
//      -> no runtime-indexed register arrays),
//   2. order-preserving compaction into LDS via prefix scan,
//   3. ordered serial sum of each compacted channel by one lane (the
//      irreducible sequential part: ~cnt dependent v_add_f32 on LDS data).
// cnt/sy/sx are exact integer reductions (order-free).
// -------------------------------------------------------------------------
__global__ void k_update(const float* __restrict__ x,
                         const float* __restrict__ lblf,
                         int* __restrict__ yc, int* __restrict__ xc,
                         float* __restrict__ colors) {
    __shared__ float sc0[1024], sc1[1024], sc2[1024];
    __shared__ int wsum[4];
    __shared__ int s_isy, s_isx;
    __shared__ float s_fin[3];
    int k = blockIdx.x, b = blockIdx.y;
    int t = threadIdx.x;
    int lane = t & 63, wid = t >> 6;

    int yck = yc[b * NC + k], xck = xc[b * NC + k];
    int y0 = max(0, yck - SS), y1 = min(HH, yck + SS);
    int x0 = max(0, xck - SS), x1 = min(WW, xck + SS);
    int wd = x1 - x0;
    int n = (y1 - y0) * wd;          // <= 1024 = 4 * 256 threads

    const float* xb = x + b * 3 * HH * WW;
    const float* lb = lblf + b * HH * WW;
    float kf = (float)k;

    if (t == 0) { s_isy = 0; s_isx = 0; }
    __syncthreads();

    // pass 1: match mask over this thread's 4 consecutive window-flat indices
    int mask = 0;
    int isy = 0, isx = 0;
    #pragma unroll
    for (int j = 0; j < 4; ++j) {
        int i = 4 * t + j;
        if (i < n) {
            int y = y0 + i / wd, xx = x0 + i % wd;
            if (lb[y * WW + xx] == kf) { mask |= (1 << j); isy += y; isx += xx; }
        }
    }
    int c_t = __popc(mask);

    // wave inclusive scan of per-thread counts
    int inc = c_t;
    for (int off = 1; off < 64; off <<= 1) {
        int u = __shfl_up(inc, off);
        if (lane >= off) inc += u;
    }
    if (lane == 63) wsum[wid] = inc;
    __syncthreads();
    int woff = 0;
    for (int w = 0; w < wid; ++w) woff += wsum[w];
    int pos = woff + inc - c_t;      // exclusive prefix = this thread's write base

    // pass 2: order-preserving compaction of matched colors into LDS
    #pragma unroll
    for (int j = 0; j < 4; ++j) {
        if ((mask >> j) & 1) {
            int i = 4 * t + j;
            int y = y0 + i / wd, xx = x0 + i % wd;
            int idx = y * WW + xx;
            sc0[pos] = xb[idx];
            sc1[pos] = xb[HH * WW + idx];
            sc2[pos] = xb[2 * HH * WW + idx];
            ++pos;
        }
    }
    // integer reductions (exact in any order)
    for (int off = 1; off < 64; off <<= 1) {
        isy += __shfl_xor(isy, off);
        isx += __shfl_xor(isx, off);
    }
    if (lane == 0) { atomicAdd(&s_isy, isy); atomicAdd(&s_isx, isx); }
    __syncthreads();

    int cnt = wsum[0] + wsum[1] + wsum[2] + wsum[3];

    // ordered serial channel sums: lanes 0/1/2, one channel each
    if (t < 3) {
        const float* a = (t == 0) ? sc0 : (t == 1) ? sc1 : sc2;
        float s = 0.0f;
        for (int i = 0; i < cnt; ++i) s = __fadd_rn(s, a[i]);
        s_fin[t] = s;
    }
    __syncthreads();

    if (t == 0 && cnt > 0) {
        float denom = (float)cnt;
        // reference: round(clip(sum/denom, 0, 223)); jnp.round == rint
        float nyf = rintf(fminf(fmaxf(__fdiv_rn((float)s_isy, denom), 0.0f), (float)(HH - 1)));
        float nxf = rintf(fminf(fmaxf(__fdiv_rn((float)s_isx, denom), 0.0f), (float)(WW - 1)));
        yc[b * NC + k] = (int)nyf;
        xc[b * NC + k] = (int)nxf;
        colors[(b * NC + k) * 3 + 0] = __fdiv_rn(s_fin[0], denom);
        colors[(b * NC + k) * 3 + 1] = __fdiv_rn(s_fin[1], denom);
        colors[(b * NC + k) * 3 + 2] = __fdiv_rn(s_fin[2], denom);
    }
}

// -------------------------------------------------------------------------
// Launch sequence:
//   window_scan -> resolve(+init_colors) -> assign -> update -> assign
// (MAX_ITER=2: only lbl escapes the reference loop, so the 2nd iteration's
//  update is dead and elided.)
// -------------------------------------------------------------------------
extern "C" void kernel_launch(void* const* d_in, const int* in_sizes, int n_in,
                              void* d_out, int out_size, void* d_ws, size_t ws_size,
                              hipStream_t stream) {
    const float* x = (const float*)d_in[0];      // (8,3,224,224) f32
    const float* g = (const float*)d_in[1];      // (8,1,224,224) f32
    float* out = (float*)d_out;
    float* out_cents = out;                      // 8*196*2 floats
    float* lblf = out + BB * NC * 2;             // 8*224*224 floats (labels as f32)

    // workspace layout (all < 64 KB total)
    int* yc = (int*)d_ws;                        // BB*NC
    int* xc = yc + BB * NC;                      // BB*NC
    float* colors = (float*)(xc + BB * NC);      // BB*NC*3
    float* wmin = colors + BB * NC * 3;          // BB*NC
    int* widx = (int*)(wmin + BB * NC);          // BB*NC
    int* wcnt = widx + BB * NC;                  // BB*NC

    dim3 gscan(NC, BB);
    k_window_scan<<<gscan, 64, 0, stream>>>(g, wmin, widx, wcnt);
    k_resolve<<<BB, 64, 0, stream>>>(g, x, wmin, widx, wcnt, yc, xc, colors, out_cents);

    dim3 gridA(WW / 16, HH / 16, BB);
    dim3 blkA(16, 16);
    dim3 gupd(NC, BB);
    k_assign<<<gridA, blkA, 0, stream>>>(x, yc, xc, colors, lblf);   // iter 0 assign
    k_update<<<gupd, 256, 0, stream>>>(x, lblf, yc, xc, colors);     // iter 0 update
    k_assign<<<gridA, blkA, 0, stream>>>(x, yc, xc, colors, lblf);   // iter 1 assign (final)
}

// Round 8
// 144.164 us; speedup vs baseline: 3.5999x; 1.0675x over previous
//
#include <hip/hip_runtime.h>
#include <math.h>

#define HH 224
#define WW 224
#define BB 8
#define NC 196
#define NBHD 10
#define SS 16
#define MW_OVER_S 0.625f   // M_WEIGHT / S = 10.0 / 16 (exactly representable)

// -------------------------------------------------------------------------
// Phase A of _find_minima: per (batch, centroid) window min / min-flat-index
// among equals / equal count. Fully parallel: grid (NC, BB), 1 wave.
// -------------------------------------------------------------------------
__global__ void k_window_scan(const float* __restrict__ g,
                              float* __restrict__ wmin,
                              int* __restrict__ widx,
                              int* __restrict__ wcnt) {
    int c = blockIdx.x, b = blockIdx.y;
    int lane = threadIdx.x;
    const float* gb = g + b * HH * WW;
    int gy = 8 + 16 * (c / 14), gx = 8 + 16 * (c % 14);
    int y0 = max(0, gy - NBHD), y1 = min(HH, gy + NBHD);
    int x0 = max(0, gx - NBHD), x1 = min(WW, gx + NBHD);
    int wd = x1 - x0;
    int n = (y1 - y0) * wd;

    // pass 1: window min (min-reduce is exact; no fp-ordering concern)
    float m = INFINITY;
    for (int i = lane; i < n; i += 64) {
        int y = y0 + i / wd, x = x0 + i % wd;
        m = fminf(m, gb[y * WW + x]);
    }
    for (int off = 1; off < 64; off <<= 1)
        m = fminf(m, __shfl_xor(m, off));

    // pass 2: count equals + min flat index among equals (L1/L2-hot)
    int bidx = 0x7fffffff;
    int cnt = 0;
    for (int i = lane; i < n; i += 64) {
        int y = y0 + i / wd, x = x0 + i % wd;
        int f = y * WW + x;
        if (gb[f] == m) { bidx = min(bidx, f); ++cnt; }
    }
    for (int off = 1; off < 64; off <<= 1) {
        bidx = min(bidx, __shfl_xor(bidx, off));
        cnt += __shfl_xor(cnt, off);
    }
    if (lane == 0) {
        wmin[b * NC + c] = m;
        widx[b * NC + c] = bidx;
        wcnt[b * NC + c] = cnt;
    }
}

// -------------------------------------------------------------------------
// Phase B of _find_minima: sequential occupancy resolve per batch,
// REGISTER-RESIDENT. One wave per batch. The chosen-pixel list lives
// distributed in registers (lane l, slot s holds the pixel chosen at
// iteration s*64+l); per-iteration occupancy test = 4 register compares +
// __any ballot (no LDS latency on the critical path; no per-iter barrier —
// single wave, lockstep). idx/cnt broadcast via v_readlane (VALU, uniform
// index). The LDS occ bitmap is still maintained (writes off critical path)
// but read ONLY in the rare rescan branch (multiple equal minima AND first
// occupied), preserving exact reference semantics. Results accumulate in
// distributed registers and are written coalesced at the end, fused with
// the init-colors gather.
// -------------------------------------------------------------------------
__global__ void k_resolve(const float* __restrict__ g,
                          const float* __restrict__ x,
                          const float* __restrict__ wmin,
                          const int* __restrict__ widx,
                          const int* __restrict__ wcnt,
                          int* __restrict__ yc, int* __restrict__ xc,
                          float* __restrict__ colors,
                          float* __restrict__ out_cents) {
    __shared__ unsigned char occ[HH * WW];
    int b = blockIdx.x, lane = threadIdx.x;
    const float* gb = g + b * HH * WW;
    unsigned int* occ32 = (unsigned int*)occ;
    for (int i = lane; i < (HH * WW) / 4; i += 64) occ32[i] = 0u;
    __syncthreads();

    // distributed load: lane holds data for c = s*64 + lane, s = 0..3
    int i0, i1, i2, i3 = -1;
    int n0, n1, n2, n3 = 0;
    float m0, m1, m2, m3 = 0.f;
    i0 = widx[b * NC + lane];       n0 = wcnt[b * NC + lane];       m0 = wmin[b * NC + lane];
    i1 = widx[b * NC + 64 + lane];  n1 = wcnt[b * NC + 64 + lane];  m1 = wmin[b * NC + 64 + lane];
    i2 = widx[b * NC + 128 + lane]; n2 = wcnt[b * NC + 128 + lane]; m2 = wmin[b * NC + 128 + lane];
    if (192 + lane < NC) {
        i3 = widx[b * NC + 192 + lane]; n3 = wcnt[b * NC + 192 + lane]; m3 = wmin[b * NC + 192 + lane];
    }

    int h0 = -1, h1 = -1, h2 = -1, h3 = -1;     // chosen-pixel list (distributed)
    int ry0 = 0, rx0 = 0, ry1 = 0, rx1 = 0;     // per-lane results
    int ry2 = 0, rx2 = 0, ry3 = 0, rx3 = 0;

    auto resolve_slot = [&](int S, int LIM, int idxR, int cntR, float minR,
                            int& hR, int& ryR, int& rxR) {
        for (int j = 0; j < LIM; ++j) {
            int idx = (int)__builtin_amdgcn_readlane((unsigned)idxR, (unsigned)j);
            int cnt = (int)__builtin_amdgcn_readlane((unsigned)cntR, (unsigned)j);
            int c = S * 64 + j;
            // occupancy test against the register-resident list (all slots)
            bool mine = (h0 == idx) | (h1 == idx) | (h2 == idx) | (h3 == idx);
            bool occd = __any(mine);             // wave-uniform
            int chosen;
            if (cnt == 1) {
                chosen = occd ? -1 : idx;        // unique min: take it, or no move
            } else if (!occd) {
                chosen = idx;                    // multiple equal, first (min flat) free
            } else {
                // RARE: multiple equal minima and the first is occupied -> rescan
                __syncthreads();                 // single wave: drains LDS writes
                float m = __shfl(minR, j);
                int gy = 8 + 16 * (c / 14), gx = 8 + 16 * (c % 14);
                int wy0 = max(0, gy - NBHD), wy1 = min(HH, gy + NBHD);
                int wx0 = max(0, gx - NBHD), wx1 = min(WW, gx + NBHD);
                int wd = wx1 - wx0;
                int n = (wy1 - wy0) * wd;
                int best = 0x7fffffff;
                for (int i = lane; i < n; i += 64) {
                    int y = wy0 + i / wd, xx = wx0 + i % wd;
                    int f = y * WW + xx;
                    if (gb[f] == m && !occ[f]) best = min(best, f);
                }
                for (int off = 1; off < 64; off <<= 1)
                    best = min(best, __shfl_xor(best, off));
                chosen = (best == 0x7fffffff) ? -1 : best;
            }
            int ny, nx;
            if (chosen >= 0) {
                ny = chosen / WW; nx = chosen % WW;
                if (lane == j) hR = chosen;      // append to register list
                if (lane == 0) occ[chosen] = 1;  // bitmap for rescan path only
            } else {
                ny = 8 + 16 * (c / 14); nx = 8 + 16 * (c % 14);  // keep grid centroid
            }
            if (lane == j) { ryR = ny; rxR = nx; }
        }
    };
    resolve_slot(0, 64, i0, n0, m0, h0, ry0, rx0);
    resolve_slot(1, 64, i1, n1, m1, h1, ry1, rx1);
    resolve_slot(2, 64, i2, n2, m2, h2, ry2, rx2);
    resolve_slot(3, NC - 192, i3, n3, m3, h3, ry3, rx3);

    // coalesced result writes + fused init-colors gather
    const float* xb = x + b * 3 * HH * WW;
#define WRITE_RES(S, ryR, rxR)                                      \
    do {                                                            \
        int c = (S) * 64 + lane;                                    \
        if (c < NC) {                                               \
            yc[b * NC + c] = ryR; xc[b * NC + c] = rxR;             \
            out_cents[(b * NC + c) * 2 + 0] = (float)ryR;           \
            out_cents[(b * NC + c) * 2 + 1] = (float)rxR;           \
            int idx = ryR * WW + rxR;                               \
            colors[(b * NC + c) * 3 + 0] = xb[idx];                 \
            colors[(b * NC + c) * 3 + 1] = xb[HH * WW + idx];       \
            colors[(b * NC + c) * 3 + 2] = xb[2 * HH * WW + idx];   \
        }                                                           \
    } while (0)
    WRITE_RES(0, ry0, rx0);
    WRITE_RES(1, ry1, rx1);
    WRITE_RES(2, ry2, rx2);
    WRITE_RES(3, ry3, rx3);
#undef WRITE_RES
}

// -------------------------------------------------------------------------
// Assignment: one 16x16 tile per block; candidate list via bbox intersect;
// per-pixel argmin with _rn arithmetic (matches reference unfused eval);
// lexicographic (d,k) tie-break == jnp.argmin first-occurrence.
// -------------------------------------------------------------------------
__global__ void k_assign(const float* __restrict__ x,
                         const int* __restrict__ yc,
                         const int* __restrict__ xc,
                         const float* __restrict__ colors,
                         float* __restrict__ lblf) {
    __shared__ int s_yc[NC], s_xc[NC];
    __shared__ float s_c0[NC], s_c1[NC], s_c2[NC], s_cc[NC];
    __shared__ int s_cand[NC];
    __shared__ int s_n;
    int b = blockIdx.z;
    int ty0 = blockIdx.y * 16, tx0 = blockIdx.x * 16;
    int t = threadIdx.y * 16 + threadIdx.x;
    if (t == 0) s_n = 0;
    __syncthreads();
    if (t < NC) {
        int yck = yc[b * NC + t], xck = xc[b * NC + t];
        s_yc[t] = yck; s_xc[t] = xck;
        float c0 = colors[(b * NC + t) * 3 + 0];
        float c1 = colors[(b * NC + t) * 3 + 1];
        float c2 = colors[(b * NC + t) * 3 + 2];
        s_c0[t] = c0; s_c1[t] = c1; s_c2[t] = c2;
        s_cc[t] = __fadd_rn(__fadd_rn(__fmul_rn(c0, c0), __fmul_rn(c1, c1)), __fmul_rn(c2, c2));
        if (yck > ty0 - 17 && yck < ty0 + 32 && xck > tx0 - 17 && xck < tx0 + 32) {
            int p = atomicAdd(&s_n, 1);
            s_cand[p] = t;
        }
    }
    __syncthreads();

    int h = ty0 + threadIdx.y, w = tx0 + threadIdx.x;
    const float* xb = x + b * 3 * HH * WW;
    int pidx = h * WW + w;
    float x0v = xb[pidx];
    float x1v = xb[HH * WW + pidx];
    float x2v = xb[2 * HH * WW + pidx];
    float px2 = __fadd_rn(__fadd_rn(__fmul_rn(x0v, x0v), __fmul_rn(x1v, x1v)), __fmul_rn(x2v, x2v));
    float hf = (float)h, wf = (float)w;

    float best = INFINITY;
    int bestk = -1;
    int n = s_n;
    for (int i = 0; i < n; ++i) {
        int k = s_cand[i];
        int yck = s_yc[k], xck = s_xc[k];
        if (h >= yck - SS && h < yck + SS && w >= xck - SS && w < xck + SS) {
            float cross = __fadd_rn(__fadd_rn(__fmul_rn(x0v, s_c0[k]), __fmul_rn(x1v, s_c1[k])),
                                    __fmul_rn(x2v, s_c2[k]));
            float t2 = __fsub_rn(__fadd_rn(px2, s_cc[k]), __fmul_rn(2.0f, cross));
            float cd = __fsqrt_rn(fmaxf(t2, 0.0f));
            float dy = __fsub_rn(hf, (float)yck);
            float dx = __fsub_rn(wf, (float)xck);
            float sp = __fsqrt_rn(__fadd_rn(__fmul_rn(dy, dy), __fmul_rn(dx, dx)));
            float d = __fadd_rn(cd, __fmul_rn(MW_OVER_S, sp));
            if (d < best || (d == best && k < bestk)) { best = d; bestk = k; }
        }
    }
    lblf[b * HH * WW + pidx] = (float)bestk;
}

// -------------------------------------------------------------------------
// Update step, parallelized: one 256-thread block per (b, k) -> 1568 blocks.
// Preserves the EXACT fp add order of the reference's segment_sum via
// order-preserving compaction into LDS + ordered serial channel sums.
// (Validated: absmax 0.0 in round 6.)
// -------------------------------------------------------------------------
__global__ void k_update(const float* __restrict__ x,
                         const float* __restrict__ lblf,
                         int* __restrict__ yc, int* __restrict__ xc,
                         float* __restrict__ colors) {
    __shared__ float sc0[1024], sc1[1024], sc2[1024];
    __shared__ int wsum[4];
    __shared__ int s_isy, s_isx;
    __shared__ float s_fin[3];
    int k = blockIdx.x, b = blockIdx.y;
    int t = threadIdx.x;
    int lane = t & 63, wid = t >> 6;

    int yck = yc[b * NC + k], xck = xc[b * NC + k];
    int y0 = max(0, yck - SS), y1 = min(HH, yck + SS);
    int x0 = max(0, xck - SS), x1 = min(WW, xck + SS);
    int wd = x1 - x0;
    int n = (y1 - y0) * wd;          // <= 1024 = 4 * 256 threads

    const float* xb = x + b * 3 * HH * WW;
    const float* lb = lblf + b * HH * WW;
    float kf = (float)k;

    if (t == 0) { s_isy = 0; s_isx = 0; }
    __syncthreads();

    // pass 1: match mask over this thread's 4 consecutive window-flat indices
    int mask = 0;
    int isy = 0, isx = 0;
    #pragma unroll
    for (int j = 0; j < 4; ++j) {
        int i = 4 * t + j;
        if (i < n) {
            int y = y0 + i / wd, xx = x0 + i % wd;
            if (lb[y * WW + xx] == kf) { mask |= (1 << j); isy += y; isx += xx; }
        }
    }
    int c_t = __popc(mask);

    // wave inclusive scan of per-thread counts
    int inc = c_t;
    for (int off = 1; off < 64; off <<= 1) {
        int u = __shfl_up(inc, off);
        if (lane >= off) inc += u;
    }
    if (lane == 63) wsum[wid] = inc;
    __syncthreads();
    int woff = 0;
    for (int w = 0; w < wid; ++w) woff += wsum[w];
    int pos = woff + inc - c_t;      // exclusive prefix = this thread's write base

    // pass 2: order-preserving compaction of matched colors into LDS
    #pragma unroll
    for (int j = 0; j < 4; ++j) {
        if ((mask >> j) & 1) {
            int i = 4 * t + j;
            int y = y0 + i / wd, xx = x0 + i % wd;
            int idx = y * WW + xx;
            sc0[pos] = xb[idx];
            sc1[pos] = xb[HH * WW + idx];
            sc2[pos] = xb[2 * HH * WW + idx];
            ++pos;
        }
    }
    // integer reductions (exact in any order)
    for (int off = 1; off < 64; off <<= 1) {
        isy += __shfl_xor(isy, off);
        isx += __shfl_xor(isx, off);
    }
    if (lane == 0) { atomicAdd(&s_isy, isy); atomicAdd(&s_isx, isx); }
    __syncthreads();

    int cnt = wsum[0] + wsum[1] + wsum[2] + wsum[3];

    // ordered serial channel sums: lanes 0/1/2, one channel each
    if (t < 3) {
        const float* a = (t == 0) ? sc0 : (t == 1) ? sc1 : sc2;
        float s = 0.0f;
        for (int i = 0; i < cnt; ++i) s = __fadd_rn(s, a[i]);
        s_fin[t] = s;
    }
    __syncthreads();

    if (t == 0 && cnt > 0) {
        float denom = (float)cnt;
        // reference: round(clip(sum/denom, 0, 223)); jnp.round == rint
        float nyf = rintf(fminf(fmaxf(__fdiv_rn((float)s_isy, denom), 0.0f), (float)(HH - 1)));
        float nxf = rintf(fminf(fmaxf(__fdiv_rn((float)s_isx, denom), 0.0f), (float)(WW - 1)));
        yc[b * NC + k] = (int)nyf;
        xc[b * NC + k] = (int)nxf;
        colors[(b * NC + k) * 3 + 0] = __fdiv_rn(s_fin[0], denom);
        colors[(b * NC + k) * 3 + 1] = __fdiv_rn(s_fin[1], denom);
        colors[(b * NC + k) * 3 + 2] = __fdiv_rn(s_fin[2], denom);
    }
}

// -------------------------------------------------------------------------
// Launch sequence:
//   window_scan -> resolve(+init_colors) -> assign -> update -> assign
// (MAX_ITER=2: only lbl escapes the reference loop, so the 2nd iteration's
//  update is dead and elided.)
// -------------------------------------------------------------------------
extern "C" void kernel_launch(void* const* d_in, const int* in_sizes, int n_in,
                              void* d_out, int out_size, void* d_ws, size_t ws_size,
                              hipStream_t stream) {
    const float* x = (const float*)d_in[0];      // (8,3,224,224) f32
    const float* g = (const float*)d_in[1];      // (8,1,224,224) f32
    float* out = (float*)d_out;
    float* out_cents = out;                      // 8*196*2 floats
    float* lblf = out + BB * NC * 2;             // 8*224*224 floats (labels as f32)

    // workspace layout (all < 64 KB total)
    int* yc = (int*)d_ws;                        // BB*NC
    int* xc = yc + BB * NC;                      // BB*NC
    float* colors = (float*)(xc + BB * NC);      // BB*NC*3
    float* wmin = colors + BB * NC * 3;          // BB*NC
    int* widx = (int*)(wmin + BB * NC);          // BB*NC
    int* wcnt = widx + BB * NC;                  // BB*NC

    dim3 gscan(NC, BB);
    k_window_scan<<<gscan, 64, 0, stream>>>(g, wmin, widx, wcnt);
    k_resolve<<<BB, 64, 0, stream>>>(g, x, wmin, widx, wcnt, yc, xc, colors, out_cents);

    dim3 gridA(WW / 16, HH / 16, BB);
    dim3 blkA(16, 16);
    dim3 gupd(NC, BB);
    k_assign<<<gridA, blkA, 0, stream>>>(x, yc, xc, colors, lblf);   // iter 0 assign
    k_update<<<gupd, 256, 0, stream>>>(x, lblf, yc, xc, colors);     // iter 0 update
    k_assign<<<gridA, blkA, 0, stream>>>(x, yc, xc, colors, lblf);   // iter 1 assign (final)
}

// Round 9
// 108.045 us; speedup vs baseline: 4.8034x; 1.3343x over previous
//
#include <hip/hip_runtime.h>
#include <math.h>

#define HH 224
#define WW 224
#define BB 8
#define NC 196
#define NBHD 10
#define SS 16
#define MW_OVER_S 0.625f   // M_WEIGHT / S = 10.0 / 16 (exactly representable)

// -------------------------------------------------------------------------
// Phase A of _find_minima: per (batch, centroid) window min / min-flat-index
// among equals / equal count. Fully parallel: grid (NC, BB), 1 wave.
// -------------------------------------------------------------------------
__global__ void k_window_scan(const float* __restrict__ g,
                              float* __restrict__ wmin,
                              int* __restrict__ widx,
                              int* __restrict__ wcnt) {
    int c = blockIdx.x, b = blockIdx.y;
    int lane = threadIdx.x;
    const float* gb = g + b * HH * WW;
    int gy = 8 + 16 * (c / 14), gx = 8 + 16 * (c % 14);
    int y0 = max(0, gy - NBHD), y1 = min(HH, gy + NBHD);
    int x0 = max(0, gx - NBHD), x1 = min(WW, gx + NBHD);
    int wd = x1 - x0;
    int n = (y1 - y0) * wd;

    // pass 1: window min (min-reduce is exact; no fp-ordering concern)
    float m = INFINITY;
    for (int i = lane; i < n; i += 64) {
        int y = y0 + i / wd, x = x0 + i % wd;
        m = fminf(m, gb[y * WW + x]);
    }
    for (int off = 1; off < 64; off <<= 1)
        m = fminf(m, __shfl_xor(m, off));

    // pass 2: count equals + min flat index among equals (L1/L2-hot)
    int bidx = 0x7fffffff;
    int cnt = 0;
    for (int i = lane; i < n; i += 64) {
        int y = y0 + i / wd, x = x0 + i % wd;
        int f = y * WW + x;
        if (gb[f] == m) { bidx = min(bidx, f); ++cnt; }
    }
    for (int off = 1; off < 64; off <<= 1) {
        bidx = min(bidx, __shfl_xor(bidx, off));
        cnt += __shfl_xor(cnt, off);
    }
    if (lane == 0) {
        wmin[b * NC + c] = m;
        widx[b * NC + c] = bidx;
        wcnt[b * NC + c] = cnt;
    }
}

// -------------------------------------------------------------------------
// Phase B of _find_minima. KEY FACTS:
//  (a) 20x20 windows at grid pitch 16 -> only grid-NEIGHBOR centroids'
//      windows overlap -> equal window-min indices can only occur between
//      scan-order-earlier neighbors c-1, c-13, c-14, c-15.
//  (b) if ALL cnt==1, a bumped centroid occupies nothing, so
//      "idx_c taken before c" <=> "exists c'<c with idx_c' == idx_c"
//      (the minimal such c' is never itself bumped)
//      <=> one of the 4 earlier neighbors has equal idx.
//  => When no ties exist (wave-uniform __any over cnt), the resolve is
//     FULLY PARALLEL and branch-free. Otherwise fall back to the exact
//     sequential occupancy loop (validated in rounds 4-8; never taken for
//     continuous random input).
// Tail: fused init-colors gather + coalesced result writes.
// -------------------------------------------------------------------------
__global__ void k_resolve(const float* __restrict__ g,
                          const float* __restrict__ x,
                          const float* __restrict__ wmin,
                          const int* __restrict__ widx,
                          const int* __restrict__ wcnt,
                          int* __restrict__ yc, int* __restrict__ xc,
                          float* __restrict__ colors,
                          float* __restrict__ out_cents) {
    __shared__ int s_idx[NC];
    __shared__ int s_cnt[NC];
    __shared__ float s_minv[NC];
    __shared__ unsigned char occ[HH * WW];   // fallback path only
    int b = blockIdx.x, lane = threadIdx.x;
    const float* gb = g + b * HH * WW;
    const float* xb = x + b * 3 * HH * WW;

    for (int i = lane; i < NC; i += 64) {
        s_idx[i] = widx[b * NC + i];
        s_cnt[i] = wcnt[b * NC + i];
        s_minv[i] = wmin[b * NC + i];
    }
    __syncthreads();

    bool tie = false;
    for (int i = lane; i < NC; i += 64) tie |= (s_cnt[i] > 1);
    if (!__any(tie)) {
        // ---- fast path: parallel winner resolve (all window minima unique)
        for (int c = lane; c < NC; c += 64) {
            int idx = s_idx[c];
            int row = c / 14, col = c % 14;
            bool bumped = (col > 0 && s_idx[c - 1] == idx);
            if (row > 0) {
                bumped |= (s_idx[c - 14] == idx);
                if (col > 0)  bumped |= (s_idx[c - 15] == idx);
                if (col < 13) bumped |= (s_idx[c - 13] == idx);
            }
            int ny, nx;
            if (bumped) { ny = 8 + 16 * row; nx = 8 + 16 * col; }   // keep grid centroid
            else        { ny = idx / WW;     nx = idx % WW;     }
            yc[b * NC + c] = ny; xc[b * NC + c] = nx;
            out_cents[(b * NC + c) * 2 + 0] = (float)ny;
            out_cents[(b * NC + c) * 2 + 1] = (float)nx;
            int p = ny * WW + nx;
            colors[(b * NC + c) * 3 + 0] = xb[p];
            colors[(b * NC + c) * 3 + 1] = xb[HH * WW + p];
            colors[(b * NC + c) * 3 + 2] = xb[2 * HH * WW + p];
        }
        return;
    }

    // ---- fallback: exact sequential occupancy resolve (rare: ties exist)
    unsigned int* occ32 = (unsigned int*)occ;
    for (int i = lane; i < (HH * WW) / 4; i += 64) occ32[i] = 0u;
    __syncthreads();

    for (int c = 0; c < NC; ++c) {
        int idx = s_idx[c];
        int cnt = s_cnt[c];
        bool occd = (occ[idx] != 0);      // wave-uniform broadcast read
        int chosen;
        if (cnt == 1) {
            chosen = occd ? -1 : idx;
        } else if (!occd) {
            chosen = idx;
        } else {
            // multiple equal minima and the first is occupied -> rescan
            float m = s_minv[c];
            int gy = 8 + 16 * (c / 14), gx = 8 + 16 * (c % 14);
            int wy0 = max(0, gy - NBHD), wy1 = min(HH, gy + NBHD);
            int wx0 = max(0, gx - NBHD), wx1 = min(WW, gx + NBHD);
            int wd = wx1 - wx0;
            int n = (wy1 - wy0) * wd;
            int best = 0x7fffffff;
            for (int i = lane; i < n; i += 64) {
                int y = wy0 + i / wd, xx = wx0 + i % wd;
                int f = y * WW + xx;
                if (gb[f] == m && !occ[f]) best = min(best, f);
            }
            for (int off = 1; off < 64; off <<= 1)
                best = min(best, __shfl_xor(best, off));
            chosen = (best == 0x7fffffff) ? -1 : best;
        }
        int ny, nx;
        if (chosen >= 0) {
            ny = chosen / WW; nx = chosen % WW;
            if (lane == 0) occ[chosen] = 1;
        } else {
            ny = 8 + 16 * (c / 14); nx = 8 + 16 * (c % 14);
        }
        if (lane == 0) {
            yc[b * NC + c] = ny;
            xc[b * NC + c] = nx;
            out_cents[(b * NC + c) * 2 + 0] = (float)ny;
            out_cents[(b * NC + c) * 2 + 1] = (float)nx;
        }
        __syncthreads();
    }
    for (int k = lane; k < NC; k += 64) {
        int y = yc[b * NC + k], xx = xc[b * NC + k];
        int idx = y * WW + xx;
        colors[(b * NC + k) * 3 + 0] = xb[idx];
        colors[(b * NC + k) * 3 + 1] = xb[HH * WW + idx];
        colors[(b * NC + k) * 3 + 2] = xb[2 * HH * WW + idx];
    }
}

// -------------------------------------------------------------------------
// Assignment: one 16x16 tile per block; candidate list via bbox intersect;
// per-pixel argmin with _rn arithmetic (matches reference unfused eval);
// lexicographic (d,k) tie-break == jnp.argmin first-occurrence.
// -------------------------------------------------------------------------
__global__ void k_assign(const float* __restrict__ x,
                         const int* __restrict__ yc,
                         const int* __restrict__ xc,
                         const float* __restrict__ colors,
                         float* __restrict__ lblf) {
    __shared__ int s_yc[NC], s_xc[NC];
    __shared__ float s_c0[NC], s_c1[NC], s_c2[NC], s_cc[NC];
    __shared__ int s_cand[NC];
    __shared__ int s_n;
    int b = blockIdx.z;
    int ty0 = blockIdx.y * 16, tx0 = blockIdx.x * 16;
    int t = threadIdx.y * 16 + threadIdx.x;
    if (t == 0) s_n = 0;
    __syncthreads();
    if (t < NC) {
        int yck = yc[b * NC + t], xck = xc[b * NC + t];
        s_yc[t] = yck; s_xc[t] = xck;
        float c0 = colors[(b * NC + t) * 3 + 0];
        float c1 = colors[(b * NC + t) * 3 + 1];
        float c2 = colors[(b * NC + t) * 3 + 2];
        s_c0[t] = c0; s_c1[t] = c1; s_c2[t] = c2;
        s_cc[t] = __fadd_rn(__fadd_rn(__fmul_rn(c0, c0), __fmul_rn(c1, c1)), __fmul_rn(c2, c2));
        if (yck > ty0 - 17 && yck < ty0 + 32 && xck > tx0 - 17 && xck < tx0 + 32) {
            int p = atomicAdd(&s_n, 1);
            s_cand[p] = t;
        }
    }
    __syncthreads();

    int h = ty0 + threadIdx.y, w = tx0 + threadIdx.x;
    const float* xb = x + b * 3 * HH * WW;
    int pidx = h * WW + w;
    float x0v = xb[pidx];
    float x1v = xb[HH * WW + pidx];
    float x2v = xb[2 * HH * WW + pidx];
    float px2 = __fadd_rn(__fadd_rn(__fmul_rn(x0v, x0v), __fmul_rn(x1v, x1v)), __fmul_rn(x2v, x2v));
    float hf = (float)h, wf = (float)w;

    float best = INFINITY;
    int bestk = -1;
    int n = s_n;
    for (int i = 0; i < n; ++i) {
        int k = s_cand[i];
        int yck = s_yc[k], xck = s_xc[k];
        if (h >= yck - SS && h < yck + SS && w >= xck - SS && w < xck + SS) {
            float cross = __fadd_rn(__fadd_rn(__fmul_rn(x0v, s_c0[k]), __fmul_rn(x1v, s_c1[k])),
                                    __fmul_rn(x2v, s_c2[k]));
            float t2 = __fsub_rn(__fadd_rn(px2, s_cc[k]), __fmul_rn(2.0f, cross));
            float cd = __fsqrt_rn(fmaxf(t2, 0.0f));
            float dy = __fsub_rn(hf, (float)yck);
            float dx = __fsub_rn(wf, (float)xck);
            float sp = __fsqrt_rn(__fadd_rn(__fmul_rn(dy, dy), __fmul_rn(dx, dx)));
            float d = __fadd_rn(cd, __fmul_rn(MW_OVER_S, sp));
            if (d < best || (d == best && k < bestk)) { best = d; bestk = k; }
        }
    }
    lblf[b * HH * WW + pidx] = (float)bestk;
}

// -------------------------------------------------------------------------
// Update step, parallelized: one 256-thread block per (b, k) -> 1568 blocks.
// Preserves the EXACT fp add order of the reference's segment_sum via
// order-preserving compaction into LDS + ordered serial channel sums.
// (Validated: absmax 0.0 in rounds 6 and 8.)
// -------------------------------------------------------------------------
__global__ void k_update(const float* __restrict__ x,
                         const float* __restrict__ lblf,
                         int* __restrict__ yc, int* __restrict__ xc,
                         float* __restrict__ colors) {
    __shared__ float sc0[1024], sc1[1024], sc2[1024];
    __shared__ int wsum[4];
    __shared__ int s_isy, s_isx;
    __shared__ float s_fin[3];
    int k = blockIdx.x, b = blockIdx.y;
    int t = threadIdx.x;
    int lane = t & 63, wid = t >> 6;

    int yck = yc[b * NC + k], xck = xc[b * NC + k];
    int y0 = max(0, yck - SS), y1 = min(HH, yck + SS);
    int x0 = max(0, xck - SS), x1 = min(WW, xck + SS);
    int wd = x1 - x0;
    int n = (y1 - y0) * wd;          // <= 1024 = 4 * 256 threads

    const float* xb = x + b * 3 * HH * WW;
    const float* lb = lblf + b * HH * WW;
    float kf = (float)k;

    if (t == 0) { s_isy = 0; s_isx = 0; }
    __syncthreads();

    // pass 1: match mask over this thread's 4 consecutive window-flat indices
    int mask = 0;
    int isy = 0, isx = 0;
    #pragma unroll
    for (int j = 0; j < 4; ++j) {
        int i = 4 * t + j;
        if (i < n) {
            int y = y0 + i / wd, xx = x0 + i % wd;
            if (lb[y * WW + xx] == kf) { mask |= (1 << j); isy += y; isx += xx; }
        }
    }
    int c_t = __popc(mask);

    // wave inclusive scan of per-thread counts
    int inc = c_t;
    for (int off = 1; off < 64; off <<= 1) {
        int u = __shfl_up(inc, off);
        if (lane >= off) inc += u;
    }
    if (lane == 63) wsum[wid] = inc;
    __syncthreads();
    int woff = 0;
    for (int w = 0; w < wid; ++w) woff += wsum[w];
    int pos = woff + inc - c_t;      // exclusive prefix = this thread's write base

    // pass 2: order-preserving compaction of matched colors into LDS
    #pragma unroll
    for (int j = 0; j < 4; ++j) {
        if ((mask >> j) & 1) {
            int i = 4 * t + j;
            int y = y0 + i / wd, xx = x0 + i % wd;
            int idx = y * WW + xx;
            sc0[pos] = xb[idx];
            sc1[pos] = xb[HH * WW + idx];
            sc2[pos] = xb[2 * HH * WW + idx];
            ++pos;
        }
    }
    // integer reductions (exact in any order)
    for (int off = 1; off < 64; off <<= 1) {
        isy += __shfl_xor(isy, off);
        isx += __shfl_xor(isx, off);
    }
    if (lane == 0) { atomicAdd(&s_isy, isy); atomicAdd(&s_isx, isx); }
    __syncthreads();

    int cnt = wsum[0] + wsum[1] + wsum[2] + wsum[3];

    // ordered serial channel sums: lanes 0/1/2, one channel each
    if (t < 3) {
        const float* a = (t == 0) ? sc0 : (t == 1) ? sc1 : sc2;
        float s = 0.0f;
        for (int i = 0; i < cnt; ++i) s = __fadd_rn(s, a[i]);
        s_fin[t] = s;
    }
    __syncthreads();

    if (t == 0 && cnt > 0) {
        float denom = (float)cnt;
        // reference: round(clip(sum/denom, 0, 223)); jnp.round == rint
        float nyf = rintf(fminf(fmaxf(__fdiv_rn((float)s_isy, denom), 0.0f), (float)(HH - 1)));
        float nxf = rintf(fminf(fmaxf(__fdiv_rn((float)s_isx, denom), 0.0f), (float)(WW - 1)));
        yc[b * NC + k] = (int)nyf;
        xc[b * NC + k] = (int)nxf;
        colors[(b * NC + k) * 3 + 0] = __fdiv_rn(s_fin[0], denom);
        colors[(b * NC + k) * 3 + 1] = __fdiv_rn(s_fin[1], denom);
        colors[(b * NC + k) * 3 + 2] = __fdiv_rn(s_fin[2], denom);
    }
}

// -------------------------------------------------------------------------
// Launch sequence:
//   window_scan -> resolve(+init_colors) -> assign -> update -> assign
// (MAX_ITER=2: only lbl escapes the reference loop, so the 2nd iteration's
//  update is dead and elided.)
// -------------------------------------------------------------------------
extern "C" void kernel_launch(void* const* d_in, const int* in_sizes, int n_in,
                              void* d_out, int out_size, void* d_ws, size_t ws_size,
                              hipStream_t stream) {
    const float* x = (const float*)d_in[0];      // (8,3,224,224) f32
    const float* g = (const float*)d_in[1];      // (8,1,224,224) f32
    float* out = (float*)d_out;
    float* out_cents = out;                      // 8*196*2 floats
    float* lblf = out + BB * NC * 2;             // 8*224*224 floats (labels as f32)

    // workspace layout (all < 64 KB total)
    int* yc = (int*)d_ws;                        // BB*NC
    int* xc = yc + BB * NC;                      // BB*NC
    float* colors = (float*)(xc + BB * NC);      // BB*NC*3
    float* wmin = colors + BB * NC * 3;          // BB*NC
    int* widx = (int*)(wmin + BB * NC);          // BB*NC
    int* wcnt = widx + BB * NC;                  // BB*NC

    dim3 gscan(NC, BB);
    k_window_scan<<<gscan, 64, 0, stream>>>(g, wmin, widx, wcnt);
    k_resolve<<<BB, 64, 0, stream>>>(g, x, wmin, widx, wcnt, yc, xc, colors, out_cents);

    dim3 gridA(WW / 16, HH / 16, BB);
    dim3 blkA(16, 16);
    dim3 gupd(NC, BB);
    k_assign<<<gridA, blkA, 0, stream>>>(x, yc, xc, colors, lblf);   // iter 0 assign
    k_update<<<gupd, 256, 0, stream>>>(x, lblf, yc, xc, colors);     // iter 0 update
    k_assign<<<gridA, blkA, 0, stream>>>(x, yc, xc, colors, lblf);   // iter 1 assign (final)
}

// Round 11
// 93.638 us; speedup vs baseline: 5.5425x; 1.1539x over previous
//
#include <hip/hip_runtime.h>
#include <math.h>

#define HH 224
#define WW 224
#define BB 8
#define NC 196
#define NBHD 10
#define SS 16
#define MW_OVER_S 0.625f   // M_WEIGHT / S = 10.0 / 16 (exactly representable)

// -------------------------------------------------------------------------
// Phase A of _find_minima: per (batch, centroid) window min / min-flat-index
// among equals / equal count. Fully parallel: grid (NC, BB), 1 wave.
// (Validated rounds 4-9.)
// -------------------------------------------------------------------------
__global__ void k_window_scan(const float* __restrict__ g,
                              float* __restrict__ wmin,
                              int* __restrict__ widx,
                              int* __restrict__ wcnt) {
    int c = blockIdx.x, b = blockIdx.y;
    int lane = threadIdx.x;
    const float* gb = g + b * HH * WW;
    int gy = 8 + 16 * (c / 14), gx = 8 + 16 * (c % 14);
    int y0 = max(0, gy - NBHD), y1 = min(HH, gy + NBHD);
    int x0 = max(0, gx - NBHD), x1 = min(WW, gx + NBHD);
    int wd = x1 - x0;
    int n = (y1 - y0) * wd;

    // pass 1: window min (min-reduce is exact; no fp-ordering concern)
    float m = INFINITY;
    for (int i = lane; i < n; i += 64) {
        int y = y0 + i / wd, x = x0 + i % wd;
        m = fminf(m, gb[y * WW + x]);
    }
    for (int off = 1; off < 64; off <<= 1)
        m = fminf(m, __shfl_xor(m, off));

    // pass 2: count equals + min flat index among equals (L1/L2-hot)
    int bidx = 0x7fffffff;
    int cnt = 0;
    for (int i = lane; i < n; i += 64) {
        int y = y0 + i / wd, x = x0 + i % wd;
        int f = y * WW + x;
        if (gb[f] == m) { bidx = min(bidx, f); ++cnt; }
    }
    for (int off = 1; off < 64; off <<= 1) {
        bidx = min(bidx, __shfl_xor(bidx, off));
        cnt += __shfl_xor(cnt, off);
    }
    if (lane == 0) {
        wmin[b * NC + c] = m;
        widx[b * NC + c] = bidx;
        wcnt[b * NC + c] = cnt;
    }
}

// -------------------------------------------------------------------------
// Phase B of _find_minima: parallel winner resolve when all window minima
// are unique (20x20 windows at pitch 16 -> only grid-neighbor windows
// overlap; "bumped" <=> an earlier neighbor has equal idx). Fallback to the
// exact sequential occupancy loop if any tie exists (never taken for
// continuous random input). Validated round 9 (absmax 0.0).
// Tail: fused init-colors gather + coalesced result writes.
// -------------------------------------------------------------------------
__global__ void k_resolve(const float* __restrict__ g,
                          const float* __restrict__ x,
                          const float* __restrict__ wmin,
                          const int* __restrict__ widx,
                          const int* __restrict__ wcnt,
                          int* __restrict__ yc, int* __restrict__ xc,
                          float* __restrict__ colors,
                          float* __restrict__ out_cents) {
    __shared__ int s_idx[NC];
    __shared__ int s_cnt[NC];
    __shared__ float s_minv[NC];
    __shared__ unsigned char occ[HH * WW];   // fallback path only
    int b = blockIdx.x, lane = threadIdx.x;
    const float* gb = g + b * HH * WW;
    const float* xb = x + b * 3 * HH * WW;

    for (int i = lane; i < NC; i += 64) {
        s_idx[i] = widx[b * NC + i];
        s_cnt[i] = wcnt[b * NC + i];
        s_minv[i] = wmin[b * NC + i];
    }
    __syncthreads();

    bool tie = false;
    for (int i = lane; i < NC; i += 64) tie |= (s_cnt[i] > 1);
    if (!__any(tie)) {
        // ---- fast path: parallel winner resolve (all window minima unique)
        for (int c = lane; c < NC; c += 64) {
            int idx = s_idx[c];
            int row = c / 14, col = c % 14;
            bool bumped = (col > 0 && s_idx[c - 1] == idx);
            if (row > 0) {
                bumped |= (s_idx[c - 14] == idx);
                if (col > 0)  bumped |= (s_idx[c - 15] == idx);
                if (col < 13) bumped |= (s_idx[c - 13] == idx);
            }
            int ny, nx;
            if (bumped) { ny = 8 + 16 * row; nx = 8 + 16 * col; }   // keep grid centroid
            else        { ny = idx / WW;     nx = idx % WW;     }
            yc[b * NC + c] = ny; xc[b * NC + c] = nx;
            out_cents[(b * NC + c) * 2 + 0] = (float)ny;
            out_cents[(b * NC + c) * 2 + 1] = (float)nx;
            int p = ny * WW + nx;
            colors[(b * NC + c) * 3 + 0] = xb[p];
            colors[(b * NC + c) * 3 + 1] = xb[HH * WW + p];
            colors[(b * NC + c) * 3 + 2] = xb[2 * HH * WW + p];
        }
        return;
    }

    // ---- fallback: exact sequential occupancy resolve (rare: ties exist)
    unsigned int* occ32 = (unsigned int*)occ;
    for (int i = lane; i < (HH * WW) / 4; i += 64) occ32[i] = 0u;
    __syncthreads();

    for (int c = 0; c < NC; ++c) {
        int idx = s_idx[c];
        int cnt = s_cnt[c];
        bool occd = (occ[idx] != 0);      // wave-uniform broadcast read
        int chosen;
        if (cnt == 1) {
            chosen = occd ? -1 : idx;
        } else if (!occd) {
            chosen = idx;
        } else {
            // multiple equal minima and the first is occupied -> rescan
            float m = s_minv[c];
            int gy = 8 + 16 * (c / 14), gx = 8 + 16 * (c % 14);
            int wy0 = max(0, gy - NBHD), wy1 = min(HH, gy + NBHD);
            int wx0 = max(0, gx - NBHD), wx1 = min(WW, gx + NBHD);
            int wd = wx1 - wx0;
            int n = (wy1 - wy0) * wd;
            int best = 0x7fffffff;
            for (int i = lane; i < n; i += 64) {
                int y = wy0 + i / wd, xx = wx0 + i % wd;
                int f = y * WW + xx;
                if (gb[f] == m && !occ[f]) best = min(best, f);
            }
            for (int off = 1; off < 64; off <<= 1)
                best = min(best, __shfl_xor(best, off));
            chosen = (best == 0x7fffffff) ? -1 : best;
        }
        int ny, nx;
        if (chosen >= 0) {
            ny = chosen / WW; nx = chosen % WW;
            if (lane == 0) occ[chosen] = 1;
        } else {
            ny = 8 + 16 * (c / 14); nx = 8 + 16 * (c % 14);
        }
        if (lane == 0) {
            yc[b * NC + c] = ny;
            xc[b * NC + c] = nx;
            out_cents[(b * NC + c) * 2 + 0] = (float)ny;
            out_cents[(b * NC + c) * 2 + 1] = (float)nx;
        }
        __syncthreads();
    }
    for (int k = lane; k < NC; k += 64) {
        int y = yc[b * NC + k], xx = xc[b * NC + k];
        int idx = y * WW + xx;
        colors[(b * NC + k) * 3 + 0] = xb[idx];
        colors[(b * NC + k) * 3 + 1] = xb[HH * WW + idx];
        colors[(b * NC + k) * 3 + 2] = xb[2 * HH * WW + idx];
    }
}

// -------------------------------------------------------------------------
// Assignment: one 16x16 tile per block; candidate list via bbox intersect
// built with WAVE-BALLOT COMPACTION (no LDS atomic serialization; candidate
// order differs from the atomicAdd version but the (d,k) lexicographic
// tie-break makes the argmin order-independent). Per-pixel argmin with _rn
// arithmetic matching the reference's unfused eval.
// -------------------------------------------------------------------------
__global__ void k_assign(const float* __restrict__ x,
                         const int* __restrict__ yc,
                         const int* __restrict__ xc,
                         const float* __restrict__ colors,
                         float* __restrict__ lblf) {
    __shared__ int s_yc[NC], s_xc[NC];
    __shared__ float s_c0[NC], s_c1[NC], s_c2[NC], s_cc[NC];
    __shared__ int s_cand[NC];
    __shared__ int s_wc[4];
    int b = blockIdx.z;
    int ty0 = blockIdx.y * 16, tx0 = blockIdx.x * 16;
    int t = threadIdx.y * 16 + threadIdx.x;
    int lane = t & 63, wid = t >> 6;

    bool pred = false;
    if (t < NC) {
        int yck = yc[b * NC + t], xck = xc[b * NC + t];
        s_yc[t] = yck; s_xc[t] = xck;
        float c0 = colors[(b * NC + t) * 3 + 0];
        float c1 = colors[(b * NC + t) * 3 + 1];
        float c2 = colors[(b * NC + t) * 3 + 2];
        s_c0[t] = c0; s_c1[t] = c1; s_c2[t] = c2;
        s_cc[t] = __fadd_rn(__fadd_rn(__fmul_rn(c0, c0), __fmul_rn(c1, c1)), __fmul_rn(c2, c2));
        // window [yck-16,yck+16)x[xck-16,xck+16) intersects tile?
        pred = (yck > ty0 - 17 && yck < ty0 + 32 && xck > tx0 - 17 && xck < tx0 + 32);
    }
    unsigned long long bm = __ballot(pred);
    if (lane == 0) s_wc[wid] = __popcll(bm);
    __syncthreads();
    int base = 0;
    for (int w = 0; w < wid; ++w) base += s_wc[w];
    if (pred) {
        int pos = base + __popcll(bm & ((1ull << lane) - 1ull));
        s_cand[pos] = t;
    }
    int n = s_wc[0] + s_wc[1] + s_wc[2] + s_wc[3];
    __syncthreads();

    int h = ty0 + threadIdx.y, w = tx0 + threadIdx.x;
    const float* xb = x + b * 3 * HH * WW;
    int pidx = h * WW + w;
    float x0v = xb[pidx];
    float x1v = xb[HH * WW + pidx];
    float x2v = xb[2 * HH * WW + pidx];
    float px2 = __fadd_rn(__fadd_rn(__fmul_rn(x0v, x0v), __fmul_rn(x1v, x1v)), __fmul_rn(x2v, x2v));
    float hf = (float)h, wf = (float)w;

    float best = INFINITY;
    int bestk = -1;
    for (int i = 0; i < n; ++i) {
        int k = s_cand[i];
        int yck = s_yc[k], xck = s_xc[k];
        if (h >= yck - SS && h < yck + SS && w >= xck - SS && w < xck + SS) {
            float cross = __fadd_rn(__fadd_rn(__fmul_rn(x0v, s_c0[k]), __fmul_rn(x1v, s_c1[k])),
                                    __fmul_rn(x2v, s_c2[k]));
            float t2 = __fsub_rn(__fadd_rn(px2, s_cc[k]), __fmul_rn(2.0f, cross));
            float cd = __fsqrt_rn(fmaxf(t2, 0.0f));
            float dy = __fsub_rn(hf, (float)yck);
            float dx = __fsub_rn(wf, (float)xck);
            float sp = __fsqrt_rn(__fadd_rn(__fmul_rn(dy, dy), __fmul_rn(dx, dx)));
            float d = __fadd_rn(cd, __fmul_rn(MW_OVER_S, sp));
            if (d < best || (d == best && k < bestk)) { best = d; bestk = k; }
        }
    }
    lblf[b * HH * WW + pidx] = (float)bestk;
}

// -------------------------------------------------------------------------
// Update step: one 256-thread block per (b, k). Order-preserving compaction
// into LDS (validated absmax 0.0), then the ordered serial channel sums are
// SOFTWARE-PIPELINED: unroll-by-8 with two float4 LDS loads per step, then
// 8 ordered __fadd_rn. The add SEQUENCE is identical to the plain loop
// (same left-fold order); only load issue is batched -> the block critical
// path drops from ~cnt*LDS-latency to ~cnt*fadd-latency.
// alignas(16) on the LDS arrays guarantees the ds_read_b128 alignment the
// float4 cast asserts.
// -------------------------------------------------------------------------
__global__ void k_update(const float* __restrict__ x,
                         const float* __restrict__ lblf,
                         int* __restrict__ yc, int* __restrict__ xc,
                         float* __restrict__ colors) {
    __shared__ alignas(16) float sc0[1024];
    __shared__ alignas(16) float sc1[1024];
    __shared__ alignas(16) float sc2[1024];
    __shared__ int wsum[4];
    __shared__ int s_isy, s_isx;
    __shared__ float s_fin[3];
    int k = blockIdx.x, b = blockIdx.y;
    int t = threadIdx.x;
    int lane = t & 63, wid = t >> 6;

    int yck = yc[b * NC + k], xck = xc[b * NC + k];
    int y0 = max(0, yck - SS), y1 = min(HH, yck + SS);
    int x0 = max(0, xck - SS), x1 = min(WW, xck + SS);
    int wd = x1 - x0;
    int n = (y1 - y0) * wd;          // <= 1024 = 4 * 256 threads

    const float* xb = x + b * 3 * HH * WW;
    const float* lb = lblf + b * HH * WW;
    float kf = (float)k;

    if (t == 0) { s_isy = 0; s_isx = 0; }
    __syncthreads();

    // pass 1: match mask over this thread's 4 consecutive window-flat indices
    int mask = 0;
    int isy = 0, isx = 0;
    #pragma unroll
    for (int j = 0; j < 4; ++j) {
        int i = 4 * t + j;
        if (i < n) {
            int y = y0 + i / wd, xx = x0 + i % wd;
            if (lb[y * WW + xx] == kf) { mask |= (1 << j); isy += y; isx += xx; }
        }
    }
    int c_t = __popc(mask);

    // wave inclusive scan of per-thread counts
    int inc = c_t;
    for (int off = 1; off < 64; off <<= 1) {
        int u = __shfl_up(inc, off);
        if (lane >= off) inc += u;
    }
    if (lane == 63) wsum[wid] = inc;
    __syncthreads();
    int woff = 0;
    for (int w = 0; w < wid; ++w) woff += wsum[w];
    int pos = woff + inc - c_t;      // exclusive prefix = this thread's write base

    // pass 2: order-preserving compaction of matched colors into LDS
    #pragma unroll
    for (int j = 0; j < 4; ++j) {
        if ((mask >> j) & 1) {
            int i = 4 * t + j;
            int y = y0 + i / wd, xx = x0 + i % wd;
            int idx = y * WW + xx;
            sc0[pos] = xb[idx];
            sc1[pos] = xb[HH * WW + idx];
            sc2[pos] = xb[2 * HH * WW + idx];
            ++pos;
        }
    }
    // integer reductions (exact in any order)
    for (int off = 1; off < 64; off <<= 1) {
        isy += __shfl_xor(isy, off);
        isx += __shfl_xor(isx, off);
    }
    if (lane == 0) { atomicAdd(&s_isy, isy); atomicAdd(&s_isx, isx); }
    __syncthreads();

    int cnt = wsum[0] + wsum[1] + wsum[2] + wsum[3];

    // ordered serial channel sums, pipelined: lanes 0/1/2, one channel each
    if (t < 3) {
        const float* a = (t == 0) ? sc0 : (t == 1) ? sc1 : sc2;
        float s = 0.0f;
        int i = 0;
        for (; i + 8 <= cnt; i += 8) {
            float4 q0 = *(const float4*)(a + i);      // ds_read_b128
            float4 q1 = *(const float4*)(a + i + 4);  // ds_read_b128
            s = __fadd_rn(s, q0.x); s = __fadd_rn(s, q0.y);
            s = __fadd_rn(s, q0.z); s = __fadd_rn(s, q0.w);
            s = __fadd_rn(s, q1.x); s = __fadd_rn(s, q1.y);
            s = __fadd_rn(s, q1.z); s = __fadd_rn(s, q1.w);
        }
        for (; i < cnt; ++i) s = __fadd_rn(s, a[i]);
        s_fin[t] = s;
    }
    __syncthreads();

    if (t == 0 && cnt > 0) {
        float denom = (float)cnt;
        // reference: round(clip(sum/denom, 0, 223)); jnp.round == rint
        float nyf = rintf(fminf(fmaxf(__fdiv_rn((float)s_isy, denom), 0.0f), (float)(HH - 1)));
        float nxf = rintf(fminf(fmaxf(__fdiv_rn((float)s_isx, denom), 0.0f), (float)(WW - 1)));
        yc[b * NC + k] = (int)nyf;
        xc[b * NC + k] = (int)nxf;
        colors[(b * NC + k) * 3 + 0] = __fdiv_rn(s_fin[0], denom);
        colors[(b * NC + k) * 3 + 1] = __fdiv_rn(s_fin[1], denom);
        colors[(b * NC + k) * 3 + 2] = __fdiv_rn(s_fin[2], denom);
    }
}

// -------------------------------------------------------------------------
// Launch sequence:
//   window_scan -> resolve(+init_colors) -> assign -> update -> assign
// (MAX_ITER=2: only lbl escapes the reference loop, so the 2nd iteration's
//  update is dead and elided.)
// -------------------------------------------------------------------------
extern "C" void kernel_launch(void* const* d_in, const int* in_sizes, int n_in,
                              void* d_out, int out_size, void* d_ws, size_t ws_size,
                              hipStream_t stream) {
    const float* x = (const float*)d_in[0];      // (8,3,224,224) f32
    const float* g = (const float*)d_in[1];      // (8,1,224,224) f32
    float* out = (float*)d_out;
    float* out_cents = out;                      // 8*196*2 floats
    float* lblf = out + BB * NC * 2;             // 8*224*224 floats (labels as f32)

    // workspace layout (all < 64 KB total)
    int* yc = (int*)d_ws;                        // BB*NC
    int* xc = yc + BB * NC;                      // BB*NC
    float* colors = (float*)(xc + BB * NC);      // BB*NC*3
    float* wmin = colors + BB * NC * 3;          // BB*NC
    int* widx = (int*)(wmin + BB * NC);          // BB*NC
    int* wcnt = widx + BB * NC;                  // BB*NC

    dim3 gscan(NC, BB);
    k_window_scan<<<gscan, 64, 0, stream>>>(g, wmin, widx, wcnt);
    k_resolve<<<BB, 64, 0, stream>>>(g, x, wmin, widx, wcnt, yc, xc, colors, out_cents);

    dim3 gridA(WW / 16, HH / 16, BB);
    dim3 blkA(16, 16);
    dim3 gupd(NC, BB);
    k_assign<<<gridA, blkA, 0, stream>>>(x, yc, xc, colors, lblf);   // iter 0 assign
    k_update<<<gupd, 256, 0, stream>>>(x, lblf, yc, xc, colors);     // iter 0 update
    k_assign<<<gridA, blkA, 0, stream>>>(x, yc, xc, colors, lblf);   // iter 1 assign (final)
}